// Round 1
// baseline (427.867 us; speedup 1.0000x reference)
//
#include <hip/hip_runtime.h>
#include <hip/hip_bf16.h>

#define C_IN   256
#define C_FEAT 256
#define C_ATT  64
#define T_FR   8
#define NB     8
#define HW     4096
#define NROW   4096                              // NB * T_FR * C_ATT rows of atten
#define CTX_ELEMS (NB * C_FEAT * T_FR * C_ATT)   // 1,048,576

typedef __attribute__((ext_vector_type(8))) short short8;
typedef __attribute__((ext_vector_type(4))) float f32x4;

__device__ __forceinline__ unsigned short f2bf(float f) {
  union { float f; unsigned int u; } v; v.f = f;
  unsigned int r = v.u + 0x7fffu + ((v.u >> 16) & 1u);   // RNE
  return (unsigned short)(r >> 16);
}

// ---------------------------------------------------------------------------
// K1: feat[b,f,p] = sum_c x[b*T+0, c, p] * W_feat[f,c] + b_feat[f]  (f32)
//     store bf16 into ws (consumed by context MFMA GEMM).
// tile 64f x 64p, K-step 16, 256 threads, 4x4 outputs/thread.
// ---------------------------------------------------------------------------
__global__ __launch_bounds__(256) void k_feat(
    const float* __restrict__ x, const float* __restrict__ Wf,
    const float* __restrict__ bfeat, unsigned short* __restrict__ featbf) {
  const int p0 = blockIdx.x * 64;
  const int f0 = blockIdx.y * 64;
  const int b  = blockIdx.z;
  const float* xp = x + (size_t)b * T_FR * C_IN * HW;   // frame 0 of clip b
  __shared__ float Wt[16][64];
  __shared__ float Xt[16][65];
  const int tid = threadIdx.x;
  const int tx = tid & 15, ty = tid >> 4;
  float acc[4][4] = {};
  for (int kc = 0; kc < C_IN; kc += 16) {
#pragma unroll
    for (int i = 0; i < 4; ++i) {
      int idx = tid + i * 256;
      Wt[idx & 15][idx >> 4] = Wf[(f0 + (idx >> 4)) * C_IN + kc + (idx & 15)];
    }
#pragma unroll
    for (int i = 0; i < 4; ++i) {
      int idx = tid + i * 256;
      Xt[idx >> 6][idx & 63] = xp[(size_t)(kc + (idx >> 6)) * HW + p0 + (idx & 63)];
    }
    __syncthreads();
#pragma unroll
    for (int k = 0; k < 16; ++k) {
      float av[4], bv[4];
#pragma unroll
      for (int i = 0; i < 4; ++i) av[i] = Wt[k][ty * 4 + i];
#pragma unroll
      for (int j = 0; j < 4; ++j) bv[j] = Xt[k][tx * 4 + j];
#pragma unroll
      for (int i = 0; i < 4; ++i)
#pragma unroll
        for (int j = 0; j < 4; ++j) acc[i][j] += av[i] * bv[j];
    }
    __syncthreads();
  }
#pragma unroll
  for (int i = 0; i < 4; ++i) {
    const int f = f0 + ty * 4 + i;
    const float bias = bfeat[f];
    ushort4 u;
    u.x = f2bf(acc[i][0] + bias);
    u.y = f2bf(acc[i][1] + bias);
    u.z = f2bf(acc[i][2] + bias);
    u.w = f2bf(acc[i][3] + bias);
    *(ushort4*)&featbf[(size_t)(b * C_FEAT + f) * HW + p0 + tx * 4] = u;
  }
}

// ---------------------------------------------------------------------------
// K2: atten logits for every frame s, write exp(logit) (f32) into the atten
//     slot of d_out (softmax normalization happens in K3).
// tile 64a x 64p (full c_atten), K-step 16.
// ---------------------------------------------------------------------------
__global__ __launch_bounds__(256) void k_att(
    const float* __restrict__ x, const float* __restrict__ Wa,
    const float* __restrict__ batt, float* __restrict__ attn) {
  const int p0 = blockIdx.x * 64;
  const int s  = blockIdx.y;           // 0..63
  const float* xp = x + (size_t)s * C_IN * HW;
  __shared__ float Wt[16][64];
  __shared__ float Xt[16][65];
  const int tid = threadIdx.x;
  const int tx = tid & 15, ty = tid >> 4;
  float acc[4][4] = {};
  for (int kc = 0; kc < C_IN; kc += 16) {
#pragma unroll
    for (int i = 0; i < 4; ++i) {
      int idx = tid + i * 256;
      Wt[idx & 15][idx >> 4] = Wa[(idx >> 4) * C_IN + kc + (idx & 15)];
    }
#pragma unroll
    for (int i = 0; i < 4; ++i) {
      int idx = tid + i * 256;
      Xt[idx >> 6][idx & 63] = xp[(size_t)(kc + (idx >> 6)) * HW + p0 + (idx & 63)];
    }
    __syncthreads();
#pragma unroll
    for (int k = 0; k < 16; ++k) {
      float av[4], bv[4];
#pragma unroll
      for (int i = 0; i < 4; ++i) av[i] = Wt[k][ty * 4 + i];
#pragma unroll
      for (int j = 0; j < 4; ++j) bv[j] = Xt[k][tx * 4 + j];
#pragma unroll
      for (int i = 0; i < 4; ++i)
#pragma unroll
        for (int j = 0; j < 4; ++j) acc[i][j] += av[i] * bv[j];
    }
    __syncthreads();
  }
  const int b = s >> 3, t = s & 7;
#pragma unroll
  for (int i = 0; i < 4; ++i) {
    const int a = ty * 4 + i;
    const float bias = batt[a];
    const size_t row = (size_t)(b * (T_FR * C_ATT) + t * C_ATT + a);
    float4 v;
    v.x = __expf(acc[i][0] + bias);
    v.y = __expf(acc[i][1] + bias);
    v.z = __expf(acc[i][2] + bias);
    v.w = __expf(acc[i][3] + bias);
    *(float4*)&attn[row * HW + p0 + tx * 4] = v;
  }
}

// ---------------------------------------------------------------------------
// K3: per-row softmax normalization. One block per (b, t*64+a) row.
//     Reads exp-values, computes sum, writes normalized f32 back in place
//     and a bf16 copy into ws for the context GEMM.
// ---------------------------------------------------------------------------
__global__ __launch_bounds__(256) void k_softmax(
    float* __restrict__ attn, unsigned short* __restrict__ attbf) {
  const int row = blockIdx.x;
  float* arow = attn + (size_t)row * HW;
  unsigned short* brow = attbf + (size_t)row * HW;
  const int tid = threadIdx.x;
  float4 v[4];
  float s = 0.f;
#pragma unroll
  for (int i = 0; i < 4; ++i) {
    v[i] = ((const float4*)arow)[tid + i * 256];
    s += v[i].x + v[i].y + v[i].z + v[i].w;
  }
#pragma unroll
  for (int off = 32; off > 0; off >>= 1) s += __shfl_down(s, off);
  __shared__ float wsum[4];
  if ((tid & 63) == 0) wsum[tid >> 6] = s;
  __syncthreads();
  const float inv = 1.0f / (wsum[0] + wsum[1] + wsum[2] + wsum[3]);
#pragma unroll
  for (int i = 0; i < 4; ++i) {
    float4 w = v[i];
    w.x *= inv; w.y *= inv; w.z *= inv; w.w *= inv;
    ((float4*)arow)[tid + i * 256] = w;
    ushort4 u;
    u.x = f2bf(w.x); u.y = f2bf(w.y); u.z = f2bf(w.z); u.w = f2bf(w.w);
    ((ushort4*)brow)[tid + i * 256] = u;
  }
}

// ---------------------------------------------------------------------------
// K4: context[b,f,a] = sum_p feat_bf16[b,f,p] * atten_bf16[b,a,p]   (f32 acc)
//     Both operands K(p)-contiguous -> classic B^T MFMA GEMM.
//     64x64 tile, BK=64, 4 waves each computing a 32x32 quadrant (2x2 frags
//     of mfma_f32_16x16x32_bf16). LDS rows padded to 72 shorts (144 B).
// ---------------------------------------------------------------------------
__global__ __launch_bounds__(256) void k_ctx(
    const unsigned short* __restrict__ featbf,
    const unsigned short* __restrict__ attbf,
    float* __restrict__ ctx) {
  const int a0 = blockIdx.x * 64;
  const int f0 = blockIdx.y * 64;
  const int b  = blockIdx.z;
  __shared__ __align__(16) unsigned short Ash[64 * 72];
  __shared__ __align__(16) unsigned short Bsh[64 * 72];
  const int tid  = threadIdx.x;
  const int lane = tid & 63;
  const int wave = tid >> 6;
  const int wf = (wave >> 1) * 32;
  const int wa = (wave & 1) * 32;
  const int r  = lane & 15;
  const int kg = lane >> 4;
  const unsigned short* Ab = featbf + (size_t)(b * C_FEAT + f0) * HW;
  const unsigned short* Bb = attbf + (size_t)(b * (T_FR * C_ATT) + a0) * HW;
  const int lrow = tid >> 3;   // 0..31
  const int lcg  = tid & 7;    // 8-element column group
  f32x4 acc[2][2] = {};
  for (int k0 = 0; k0 < HW; k0 += 64) {
    *(int4*)&Ash[lrow * 72 + lcg * 8]        = *(const int4*)&Ab[(size_t)lrow * HW + k0 + lcg * 8];
    *(int4*)&Ash[(lrow + 32) * 72 + lcg * 8] = *(const int4*)&Ab[(size_t)(lrow + 32) * HW + k0 + lcg * 8];
    *(int4*)&Bsh[lrow * 72 + lcg * 8]        = *(const int4*)&Bb[(size_t)lrow * HW + k0 + lcg * 8];
    *(int4*)&Bsh[(lrow + 32) * 72 + lcg * 8] = *(const int4*)&Bb[(size_t)(lrow + 32) * HW + k0 + lcg * 8];
    __syncthreads();
#pragma unroll
    for (int ks = 0; ks < 2; ++ks) {
      short8 afr[2], bfr[2];
#pragma unroll
      for (int mi = 0; mi < 2; ++mi)
        afr[mi] = *(const short8*)&Ash[(wf + mi * 16 + r) * 72 + ks * 32 + kg * 8];
#pragma unroll
      for (int nj = 0; nj < 2; ++nj)
        bfr[nj] = *(const short8*)&Bsh[(wa + nj * 16 + r) * 72 + ks * 32 + kg * 8];
#pragma unroll
      for (int mi = 0; mi < 2; ++mi)
#pragma unroll
        for (int nj = 0; nj < 2; ++nj)
          acc[mi][nj] = __builtin_amdgcn_mfma_f32_16x16x32_bf16(
              afr[mi], bfr[nj], acc[mi][nj], 0, 0, 0);
    }
    __syncthreads();
  }
#pragma unroll
  for (int mi = 0; mi < 2; ++mi)
#pragma unroll
    for (int nj = 0; nj < 2; ++nj)
#pragma unroll
      for (int reg = 0; reg < 4; ++reg) {
        const int f = f0 + wf + mi * 16 + kg * 4 + reg;   // C/D: row=(lane>>4)*4+reg
        const int a = a0 + wa + nj * 16 + r;              //      col=lane&15
        ctx[(size_t)(b * C_FEAT + f) * (T_FR * C_ATT) + a] = acc[mi][nj][reg];
      }
}

// ---------------------------------------------------------------------------
extern "C" void kernel_launch(void* const* d_in, const int* in_sizes, int n_in,
                              void* d_out, int out_size, void* d_ws, size_t ws_size,
                              hipStream_t stream) {
  const float* x     = (const float*)d_in[0];
  const float* Wf    = (const float*)d_in[1];
  const float* bfeat = (const float*)d_in[2];
  const float* Wa    = (const float*)d_in[3];
  const float* ba    = (const float*)d_in[4];
  float* ctx  = (float*)d_out;
  float* attn = (float*)d_out + CTX_ELEMS;

  unsigned short* featbf = (unsigned short*)d_ws;                       // 16.8 MB
  unsigned short* attbf  = featbf + (size_t)NB * C_FEAT * HW;           // 33.6 MB

  k_feat<<<dim3(HW / 64, C_FEAT / 64, NB), 256, 0, stream>>>(x, Wf, bfeat, featbf);
  k_att<<<dim3(HW / 64, NB * T_FR), 256, 0, stream>>>(x, Wa, ba, attn);
  k_softmax<<<NROW, 256, 0, stream>>>(attn, attbf);
  k_ctx<<<dim3((T_FR * C_ATT) / 64, C_FEAT / 64, NB), 256, 0, stream>>>(featbf, attbf, ctx);
}

// Round 2
// 160.130 us; speedup vs baseline: 2.6720x; 2.6720x over previous
//
#include <hip/hip_runtime.h>
#include <hip/hip_bf16.h>

#define HW    4096
#define CIN   256
#define NB    8
#define T_FR  8
#define CTX_ELEMS (NB * 256 * 512)      // 1,048,576 = 2^20

typedef __attribute__((ext_vector_type(8))) short short8;
typedef __attribute__((ext_vector_type(4))) float f32x4;

__device__ __forceinline__ unsigned short f2bf(float f) {
  union { float f; unsigned int u; } v; v.f = f;
  unsigned int r = v.u + 0x7fffu + ((v.u >> 16) & 1u);   // RNE
  return (unsigned short)(r >> 16);
}
__device__ __forceinline__ float bf2f(unsigned short u) {
  union { unsigned int u; float f; } v; v.u = ((unsigned int)u) << 16;
  return v.f;
}

// ---------------------------------------------------------------------------
// k_feat: feat[b,f,p] = sum_c x[b*T, c, p] * Wf[f,c] + bias  -> bf16 ws
// A = x^T (m = p, per-lane direct global column-gather, f32->bf16 cvt),
// B = Wf tile (n = 128 f) staged bf16 in LDS (264-short padded rows).
// Block: 4 waves x 32p = 128 p.  Grid (32 pblk, 2 ftile, 8 b). No K-loop barriers.
// ---------------------------------------------------------------------------
#define LROW 264
__global__ __launch_bounds__(256) void k_feat(
    const float* __restrict__ x, const float* __restrict__ Wf,
    const float* __restrict__ bfeat, unsigned short* __restrict__ featbf) {
  const int p0  = blockIdx.x * 128;
  const int f0t = blockIdx.y * 128;
  const int b   = blockIdx.z;
  __shared__ unsigned short Wsh[128 * LROW];   // 67.6 KB
  const int tid = threadIdx.x, lane = tid & 63, wave = tid >> 6;
  // stage Wf[f0t..+128][0..256] -> bf16 LDS
  {
    const int row = tid >> 1, seg = tid & 1;
    const float* src = Wf + (size_t)(f0t + row) * CIN + seg * 128;
    unsigned short* dst = &Wsh[row * LROW + seg * 128];
#pragma unroll
    for (int i = 0; i < 16; ++i) {
      float4 va = *(const float4*)(src + i * 8);
      float4 vb = *(const float4*)(src + i * 8 + 4);
      short8 w;
      w[0] = (short)f2bf(va.x); w[1] = (short)f2bf(va.y);
      w[2] = (short)f2bf(va.z); w[3] = (short)f2bf(va.w);
      w[4] = (short)f2bf(vb.x); w[5] = (short)f2bf(vb.y);
      w[6] = (short)f2bf(vb.z); w[7] = (short)f2bf(vb.w);
      *(short8*)(dst + i * 8) = w;
    }
  }
  __syncthreads();
  const int r = lane & 15, kg = lane >> 4;
  const int pw = p0 + wave * 32;
  const float* xs = x + (size_t)(b * T_FR) * CIN * HW;   // frame 0 of clip b
  f32x4 acc[2][8] = {};
  for (int ks = 0; ks < 8; ++ks) {
    short8 afr[2];
#pragma unroll
    for (int mi = 0; mi < 2; ++mi) {
      const float* col = xs + (size_t)(ks * 32 + kg * 8) * HW + pw + mi * 16 + r;
#pragma unroll
      for (int j = 0; j < 8; ++j) afr[mi][j] = (short)f2bf(col[(size_t)j * HW]);
    }
    short8 bfr[8];
#pragma unroll
    for (int nj = 0; nj < 8; ++nj)
      bfr[nj] = *(const short8*)&Wsh[(nj * 16 + r) * LROW + ks * 32 + kg * 8];
#pragma unroll
    for (int mi = 0; mi < 2; ++mi)
#pragma unroll
      for (int nj = 0; nj < 8; ++nj)
        acc[mi][nj] = __builtin_amdgcn_mfma_f32_16x16x32_bf16(afr[mi], bfr[nj], acc[mi][nj], 0, 0, 0);
  }
  // epilogue: D rows = p, cols = f.  store ushort4 along p.
#pragma unroll
  for (int nj = 0; nj < 8; ++nj) {
    const int f = f0t + nj * 16 + r;
    const float bias = bfeat[f];
#pragma unroll
    for (int mi = 0; mi < 2; ++mi) {
      ushort4 u;
      u.x = f2bf(acc[mi][nj][0] + bias);
      u.y = f2bf(acc[mi][nj][1] + bias);
      u.z = f2bf(acc[mi][nj][2] + bias);
      u.w = f2bf(acc[mi][nj][3] + bias);
      *(ushort4*)&featbf[(size_t)(b * 256 + f) * HW + pw + mi * 16 + kg * 4] = u;
    }
  }
}

// ---------------------------------------------------------------------------
// k_att: logits = Wa @ x[s] + bias; e = exp(logit); store e (bf16) to ws;
// atomicAdd per-row sums.  Same operand scheme as k_feat (n = 64 a).
// Grid (32 pblk, 64 frames).
// ---------------------------------------------------------------------------
__global__ __launch_bounds__(256) void k_att(
    const float* __restrict__ x, const float* __restrict__ Wa,
    const float* __restrict__ batt, unsigned short* __restrict__ attbf,
    float* __restrict__ rsum) {
  const int p0 = blockIdx.x * 128;
  const int s  = blockIdx.y;
  __shared__ unsigned short Wsh[64 * LROW];    // 33.8 KB
  __shared__ float wsum[4][64];
  const int tid = threadIdx.x, lane = tid & 63, wave = tid >> 6;
  {
    const int row = tid >> 2, seg = tid & 3;
    const float* src = Wa + (size_t)row * CIN + seg * 64;
    unsigned short* dst = &Wsh[row * LROW + seg * 64];
#pragma unroll
    for (int i = 0; i < 8; ++i) {
      float4 va = *(const float4*)(src + i * 8);
      float4 vb = *(const float4*)(src + i * 8 + 4);
      short8 w;
      w[0] = (short)f2bf(va.x); w[1] = (short)f2bf(va.y);
      w[2] = (short)f2bf(va.z); w[3] = (short)f2bf(va.w);
      w[4] = (short)f2bf(vb.x); w[5] = (short)f2bf(vb.y);
      w[6] = (short)f2bf(vb.z); w[7] = (short)f2bf(vb.w);
      *(short8*)(dst + i * 8) = w;
    }
  }
  __syncthreads();
  const int r = lane & 15, kg = lane >> 4;
  const int pw = p0 + wave * 32;
  const float* xs = x + (size_t)s * CIN * HW;
  f32x4 acc[2][4] = {};
  for (int ks = 0; ks < 8; ++ks) {
    short8 afr[2];
#pragma unroll
    for (int mi = 0; mi < 2; ++mi) {
      const float* col = xs + (size_t)(ks * 32 + kg * 8) * HW + pw + mi * 16 + r;
#pragma unroll
      for (int j = 0; j < 8; ++j) afr[mi][j] = (short)f2bf(col[(size_t)j * HW]);
    }
    short8 bfr[4];
#pragma unroll
    for (int nj = 0; nj < 4; ++nj)
      bfr[nj] = *(const short8*)&Wsh[(nj * 16 + r) * LROW + ks * 32 + kg * 8];
#pragma unroll
    for (int mi = 0; mi < 2; ++mi)
#pragma unroll
      for (int nj = 0; nj < 4; ++nj)
        acc[mi][nj] = __builtin_amdgcn_mfma_f32_16x16x32_bf16(afr[mi], bfr[nj], acc[mi][nj], 0, 0, 0);
  }
  const int b = s >> 3, t = s & 7;
  float rowpart[4];
#pragma unroll
  for (int nj = 0; nj < 4; ++nj) {
    const int a = nj * 16 + r;
    const float bias = batt[a];
    float sp = 0.f;
#pragma unroll
    for (int mi = 0; mi < 2; ++mi) {
      float e0 = __expf(acc[mi][nj][0] + bias);
      float e1 = __expf(acc[mi][nj][1] + bias);
      float e2 = __expf(acc[mi][nj][2] + bias);
      float e3 = __expf(acc[mi][nj][3] + bias);
      sp += e0 + e1 + e2 + e3;
      ushort4 u;
      u.x = f2bf(e0); u.y = f2bf(e1); u.z = f2bf(e2); u.w = f2bf(e3);
      *(ushort4*)&attbf[(size_t)(b * 512 + t * 64 + a) * HW + pw + mi * 16 + kg * 4] = u;
    }
    sp += __shfl_xor(sp, 16);
    sp += __shfl_xor(sp, 32);
    rowpart[nj] = sp;
  }
  if (lane < 16) {
#pragma unroll
    for (int nj = 0; nj < 4; ++nj) wsum[wave][nj * 16 + r] = rowpart[nj];
  }
  __syncthreads();
  if (tid < 64) {
    float tot = wsum[0][tid] + wsum[1][tid] + wsum[2][tid] + wsum[3][tid];
    atomicAdd(&rsum[b * 512 + t * 64 + tid], tot);
  }
}

// ---------------------------------------------------------------------------
// k_ctx: split-K(8) partial GEMM: partial[kc][b][f][a] = sum_{p in chunk}
//        feat[b,f,p]*e[b,a,p].  A = featbf direct global dwordx4 (K-contig),
//        B = attbf tile staged in LDS.  Block: 128f x 64a, K = 512.
// Grid (8 atile, 2 ftile, 64 = b*8+kc).
// ---------------------------------------------------------------------------
__global__ __launch_bounds__(256) void k_ctx(
    const unsigned short* __restrict__ featbf,
    const unsigned short* __restrict__ attbf,
    float* __restrict__ partial) {
  const int a0 = blockIdx.x * 64;
  const int ft = blockIdx.y;
  const int b  = blockIdx.z >> 3;
  const int kc = blockIdx.z & 7;
  __shared__ unsigned short Bsh[64 * LROW];    // 33.8 KB
  const int tid = threadIdx.x, lane = tid & 63, wave = tid >> 6;
  const int r = lane & 15, kg = lane >> 4;
  const int fbase = ft * 128 + wave * 32;
  const unsigned short* Arow = featbf + (size_t)(b * 256 + fbase + r) * HW + kc * 512 + kg * 8;
  const unsigned short* Bsrc = attbf + (size_t)(b * 512 + a0 + (tid >> 2)) * HW + kc * 512 + (tid & 3) * 64;
  unsigned short* Bdst = &Bsh[(tid >> 2) * LROW + (tid & 3) * 64];
  f32x4 acc[2][4] = {};
  for (int ch = 0; ch < 2; ++ch) {
    __syncthreads();
#pragma unroll
    for (int i = 0; i < 8; ++i)
      *(short8*)(Bdst + i * 8) = *(const short8*)(Bsrc + ch * 256 + i * 8);
    __syncthreads();
#pragma unroll
    for (int ks = 0; ks < 8; ++ks) {
      short8 afr[2];
      afr[0] = *(const short8*)(Arow + ch * 256 + ks * 32);
      afr[1] = *(const short8*)(Arow + ch * 256 + ks * 32 + (size_t)16 * HW);
      short8 bfr[4];
#pragma unroll
      for (int nj = 0; nj < 4; ++nj)
        bfr[nj] = *(const short8*)&Bsh[(nj * 16 + r) * LROW + ks * 32 + kg * 8];
#pragma unroll
      for (int mi = 0; mi < 2; ++mi)
#pragma unroll
        for (int nj = 0; nj < 4; ++nj)
          acc[mi][nj] = __builtin_amdgcn_mfma_f32_16x16x32_bf16(afr[mi], bfr[nj], acc[mi][nj], 0, 0, 0);
    }
  }
  const size_t base = ((size_t)kc << 20) + (size_t)b * (256 * 512);
#pragma unroll
  for (int mi = 0; mi < 2; ++mi)
#pragma unroll
    for (int nj = 0; nj < 4; ++nj)
#pragma unroll
      for (int reg = 0; reg < 4; ++reg) {
        const int f = fbase + mi * 16 + kg * 4 + reg;
        const int a = a0 + nj * 16 + r;
        partial[base + (size_t)f * 512 + a] = acc[mi][nj][reg];
      }
}

// ---------------------------------------------------------------------------
// k_ctxred: ctx[idx] = (1/rsum[row_a]) * sum_kc partial[kc][idx]
// ---------------------------------------------------------------------------
__global__ __launch_bounds__(256) void k_ctxred(
    const float* __restrict__ partial, const float* __restrict__ rsum,
    float* __restrict__ ctx) {
  const int idx = blockIdx.x * 256 + threadIdx.x;
  const int a = idx & 511, b = idx >> 17;
  float s = 0.f;
#pragma unroll
  for (int kc = 0; kc < 8; ++kc) s += partial[((size_t)kc << 20) + idx];
  ctx[idx] = s / rsum[b * 512 + a];
}

// ---------------------------------------------------------------------------
// k_attn_out: attn[row,p] = e_bf16[row,p] / rsum[row]  (f32 out)
// ---------------------------------------------------------------------------
__global__ __launch_bounds__(256) void k_attn_out(
    const unsigned short* __restrict__ attbf, const float* __restrict__ rsum,
    float* __restrict__ attn) {
  const int row = blockIdx.x;
  const float inv = 1.0f / rsum[row];
  const unsigned short* src = attbf + (size_t)row * HW;
  float* dst = attn + (size_t)row * HW;
  const int tid = threadIdx.x;
#pragma unroll
  for (int i = 0; i < 2; ++i) {
    short8 v = *(const short8*)(src + tid * 8 + i * 2048);
    float4 o0, o1;
    o0.x = bf2f((unsigned short)v[0]) * inv;
    o0.y = bf2f((unsigned short)v[1]) * inv;
    o0.z = bf2f((unsigned short)v[2]) * inv;
    o0.w = bf2f((unsigned short)v[3]) * inv;
    o1.x = bf2f((unsigned short)v[4]) * inv;
    o1.y = bf2f((unsigned short)v[5]) * inv;
    o1.z = bf2f((unsigned short)v[6]) * inv;
    o1.w = bf2f((unsigned short)v[7]) * inv;
    *(float4*)(dst + tid * 8 + i * 2048) = o0;
    *(float4*)(dst + tid * 8 + i * 2048 + 4) = o1;
  }
}

// ---------------------------------------------------------------------------
extern "C" void kernel_launch(void* const* d_in, const int* in_sizes, int n_in,
                              void* d_out, int out_size, void* d_ws, size_t ws_size,
                              hipStream_t stream) {
  const float* x     = (const float*)d_in[0];
  const float* Wf    = (const float*)d_in[1];
  const float* bfeat = (const float*)d_in[2];
  const float* Wa    = (const float*)d_in[3];
  const float* ba    = (const float*)d_in[4];
  float* ctx  = (float*)d_out;
  float* attn = ctx + CTX_ELEMS;

  unsigned short* featbf = (unsigned short*)d_ws;                 // 16.8 MB
  unsigned short* attbf  = featbf + (size_t)NB * 256 * HW;        // 33.6 MB
  float* rsum = (float*)(attbf + (size_t)4096 * HW);              // 16 KB
  float* partial = attn;   // reuse attn slot as split-K scratch (overwritten by k_attn_out last)

  hipMemsetAsync(rsum, 0, 4096 * sizeof(float), stream);
  k_feat<<<dim3(32, 2, NB), 256, 0, stream>>>(x, Wf, bfeat, featbf);
  k_att<<<dim3(32, 64), 256, 0, stream>>>(x, Wa, ba, attbf, rsum);
  k_ctx<<<dim3(8, 2, 64), 256, 0, stream>>>(featbf, attbf, partial);
  k_ctxred<<<4096, 256, 0, stream>>>(partial, rsum, ctx);
  k_attn_out<<<4096, 256, 0, stream>>>(attbf, rsum, attn);
}

// Round 3
// 156.334 us; speedup vs baseline: 2.7369x; 1.0243x over previous
//
#include <hip/hip_runtime.h>
#include <hip/hip_bf16.h>

#define HW    4096
#define CIN   256
#define NB    8
#define T_FR  8
#define CTX_ELEMS (NB * 256 * 512)      // 1,048,576 = 2^20

typedef __attribute__((ext_vector_type(8))) short short8;
typedef __attribute__((ext_vector_type(4))) float f32x4;

__device__ __forceinline__ unsigned short f2bf(float f) {
  union { float f; unsigned int u; } v; v.f = f;
  unsigned int r = v.u + 0x7fffu + ((v.u >> 16) & 1u);   // RNE
  return (unsigned short)(r >> 16);
}
__device__ __forceinline__ float bf2f(unsigned short u) {
  union { unsigned int u; float f; } v; v.u = ((unsigned int)u) << 16;
  return v.f;
}

// ---------------------------------------------------------------------------
// k_feat: feat[b,f,p] = sum_c x[b*T, c, p] * Wf[f,c] + bias  -> bf16 ws
// A = x^T (m = p, per-lane direct global column-gather, f32->bf16 cvt),
// B = Wf tile (n = 128 f) staged bf16 in LDS (264-short padded rows).
// Block: 4 waves x 32p = 128 p.  Grid (32 pblk, 2 ftile, 8 b). No K-loop barriers.
// ---------------------------------------------------------------------------
#define LROW 264
__global__ __launch_bounds__(256) void k_feat(
    const float* __restrict__ x, const float* __restrict__ Wf,
    const float* __restrict__ bfeat, unsigned short* __restrict__ featbf) {
  const int p0  = blockIdx.x * 128;
  const int f0t = blockIdx.y * 128;
  const int b   = blockIdx.z;
  __shared__ unsigned short Wsh[128 * LROW];   // 67.6 KB
  const int tid = threadIdx.x, lane = tid & 63, wave = tid >> 6;
  // stage Wf[f0t..+128][0..256] -> bf16 LDS
  {
    const int row = tid >> 1, seg = tid & 1;
    const float* src = Wf + (size_t)(f0t + row) * CIN + seg * 128;
    unsigned short* dst = &Wsh[row * LROW + seg * 128];
#pragma unroll
    for (int i = 0; i < 16; ++i) {
      float4 va = *(const float4*)(src + i * 8);
      float4 vb = *(const float4*)(src + i * 8 + 4);
      short8 w;
      w[0] = (short)f2bf(va.x); w[1] = (short)f2bf(va.y);
      w[2] = (short)f2bf(va.z); w[3] = (short)f2bf(va.w);
      w[4] = (short)f2bf(vb.x); w[5] = (short)f2bf(vb.y);
      w[6] = (short)f2bf(vb.z); w[7] = (short)f2bf(vb.w);
      *(short8*)(dst + i * 8) = w;
    }
  }
  __syncthreads();
  const int r = lane & 15, kg = lane >> 4;
  const int pw = p0 + wave * 32;
  const float* xs = x + (size_t)(b * T_FR) * CIN * HW;   // frame 0 of clip b
  f32x4 acc[2][8] = {};
  for (int ks = 0; ks < 8; ++ks) {
    short8 afr[2];
#pragma unroll
    for (int mi = 0; mi < 2; ++mi) {
      const float* col = xs + (size_t)(ks * 32 + kg * 8) * HW + pw + mi * 16 + r;
#pragma unroll
      for (int j = 0; j < 8; ++j) afr[mi][j] = (short)f2bf(col[(size_t)j * HW]);
    }
    short8 bfr[8];
#pragma unroll
    for (int nj = 0; nj < 8; ++nj)
      bfr[nj] = *(const short8*)&Wsh[(nj * 16 + r) * LROW + ks * 32 + kg * 8];
#pragma unroll
    for (int mi = 0; mi < 2; ++mi)
#pragma unroll
      for (int nj = 0; nj < 8; ++nj)
        acc[mi][nj] = __builtin_amdgcn_mfma_f32_16x16x32_bf16(afr[mi], bfr[nj], acc[mi][nj], 0, 0, 0);
  }
  // epilogue: D rows = p, cols = f.  store ushort4 along p.
#pragma unroll
  for (int nj = 0; nj < 8; ++nj) {
    const int f = f0t + nj * 16 + r;
    const float bias = bfeat[f];
#pragma unroll
    for (int mi = 0; mi < 2; ++mi) {
      ushort4 u;
      u.x = f2bf(acc[mi][nj][0] + bias);
      u.y = f2bf(acc[mi][nj][1] + bias);
      u.z = f2bf(acc[mi][nj][2] + bias);
      u.w = f2bf(acc[mi][nj][3] + bias);
      *(ushort4*)&featbf[(size_t)(b * 256 + f) * HW + pw + mi * 16 + kg * 4] = u;
    }
  }
}

// ---------------------------------------------------------------------------
// k_att: logits = Wa @ x[s] + bias; e = exp(logit); store e (bf16) to ws;
// write per-pblock row-sum partials (deterministic, no atomics, no memset).
// Grid (32 pblk, 64 frames).
// ---------------------------------------------------------------------------
__global__ __launch_bounds__(256) void k_att(
    const float* __restrict__ x, const float* __restrict__ Wa,
    const float* __restrict__ batt, unsigned short* __restrict__ attbf,
    float* __restrict__ rsum_part) {
  const int p0 = blockIdx.x * 128;
  const int s  = blockIdx.y;
  __shared__ unsigned short Wsh[64 * LROW];    // 33.8 KB
  __shared__ float wsum[4][64];
  const int tid = threadIdx.x, lane = tid & 63, wave = tid >> 6;
  {
    const int row = tid >> 2, seg = tid & 3;
    const float* src = Wa + (size_t)row * CIN + seg * 64;
    unsigned short* dst = &Wsh[row * LROW + seg * 64];
#pragma unroll
    for (int i = 0; i < 8; ++i) {
      float4 va = *(const float4*)(src + i * 8);
      float4 vb = *(const float4*)(src + i * 8 + 4);
      short8 w;
      w[0] = (short)f2bf(va.x); w[1] = (short)f2bf(va.y);
      w[2] = (short)f2bf(va.z); w[3] = (short)f2bf(va.w);
      w[4] = (short)f2bf(vb.x); w[5] = (short)f2bf(vb.y);
      w[6] = (short)f2bf(vb.z); w[7] = (short)f2bf(vb.w);
      *(short8*)(dst + i * 8) = w;
    }
  }
  __syncthreads();
  const int r = lane & 15, kg = lane >> 4;
  const int pw = p0 + wave * 32;
  const float* xs = x + (size_t)s * CIN * HW;
  f32x4 acc[2][4] = {};
  for (int ks = 0; ks < 8; ++ks) {
    short8 afr[2];
#pragma unroll
    for (int mi = 0; mi < 2; ++mi) {
      const float* col = xs + (size_t)(ks * 32 + kg * 8) * HW + pw + mi * 16 + r;
#pragma unroll
      for (int j = 0; j < 8; ++j) afr[mi][j] = (short)f2bf(col[(size_t)j * HW]);
    }
    short8 bfr[4];
#pragma unroll
    for (int nj = 0; nj < 4; ++nj)
      bfr[nj] = *(const short8*)&Wsh[(nj * 16 + r) * LROW + ks * 32 + kg * 8];
#pragma unroll
    for (int mi = 0; mi < 2; ++mi)
#pragma unroll
      for (int nj = 0; nj < 4; ++nj)
        acc[mi][nj] = __builtin_amdgcn_mfma_f32_16x16x32_bf16(afr[mi], bfr[nj], acc[mi][nj], 0, 0, 0);
  }
  const int b = s >> 3, t = s & 7;
  float rowpart[4];
#pragma unroll
  for (int nj = 0; nj < 4; ++nj) {
    const int a = nj * 16 + r;
    const float bias = batt[a];
    float sp = 0.f;
#pragma unroll
    for (int mi = 0; mi < 2; ++mi) {
      float e0 = __expf(acc[mi][nj][0] + bias);
      float e1 = __expf(acc[mi][nj][1] + bias);
      float e2 = __expf(acc[mi][nj][2] + bias);
      float e3 = __expf(acc[mi][nj][3] + bias);
      sp += e0 + e1 + e2 + e3;
      ushort4 u;
      u.x = f2bf(e0); u.y = f2bf(e1); u.z = f2bf(e2); u.w = f2bf(e3);
      *(ushort4*)&attbf[(size_t)(b * 512 + t * 64 + a) * HW + pw + mi * 16 + kg * 4] = u;
    }
    sp += __shfl_xor(sp, 16);
    sp += __shfl_xor(sp, 32);
    rowpart[nj] = sp;
  }
  if (lane < 16) {
#pragma unroll
    for (int nj = 0; nj < 4; ++nj) wsum[wave][nj * 16 + r] = rowpart[nj];
  }
  __syncthreads();
  if (tid < 64) {
    float tot = wsum[0][tid] + wsum[1][tid] + wsum[2][tid] + wsum[3][tid];
    rsum_part[(size_t)blockIdx.x * 4096 + b * 512 + t * 64 + tid] = tot;
  }
}

// ---------------------------------------------------------------------------
// k_rsum: rsum[row] = sum_{pblk<32} rsum_part[pblk][row].  16 blocks x 256.
// ---------------------------------------------------------------------------
__global__ __launch_bounds__(256) void k_rsum(
    const float* __restrict__ rsum_part, float* __restrict__ rsum) {
  const int row = blockIdx.x * 256 + threadIdx.x;
  float s = 0.f;
#pragma unroll
  for (int j = 0; j < 32; ++j) s += rsum_part[(size_t)j * 4096 + row];
  rsum[row] = s;
}

// ---------------------------------------------------------------------------
// k_ctx: split-K(8) partial GEMM: partial[kc][b][f][a] = sum_{p in chunk}
//        feat[b,f,p]*e[b,a,p].  A = featbf direct global dwordx4 (K-contig),
//        B = attbf tile staged in LDS.  Block: 128f x 64a, K = 512.
// Grid (8 atile, 2 ftile, 64 = b*8+kc).
// ---------------------------------------------------------------------------
__global__ __launch_bounds__(256) void k_ctx(
    const unsigned short* __restrict__ featbf,
    const unsigned short* __restrict__ attbf,
    float* __restrict__ partial) {
  const int a0 = blockIdx.x * 64;
  const int ft = blockIdx.y;
  const int b  = blockIdx.z >> 3;
  const int kc = blockIdx.z & 7;
  __shared__ unsigned short Bsh[64 * LROW];    // 33.8 KB
  const int tid = threadIdx.x, lane = tid & 63, wave = tid >> 6;
  const int r = lane & 15, kg = lane >> 4;
  const int fbase = ft * 128 + wave * 32;
  const unsigned short* Arow = featbf + (size_t)(b * 256 + fbase + r) * HW + kc * 512 + kg * 8;
  const unsigned short* Bsrc = attbf + (size_t)(b * 512 + a0 + (tid >> 2)) * HW + kc * 512 + (tid & 3) * 64;
  unsigned short* Bdst = &Bsh[(tid >> 2) * LROW + (tid & 3) * 64];
  f32x4 acc[2][4] = {};
  for (int ch = 0; ch < 2; ++ch) {
    __syncthreads();
#pragma unroll
    for (int i = 0; i < 8; ++i)
      *(short8*)(Bdst + i * 8) = *(const short8*)(Bsrc + ch * 256 + i * 8);
    __syncthreads();
#pragma unroll
    for (int ks = 0; ks < 8; ++ks) {
      short8 afr[2];
      afr[0] = *(const short8*)(Arow + ch * 256 + ks * 32);
      afr[1] = *(const short8*)(Arow + ch * 256 + ks * 32 + (size_t)16 * HW);
      short8 bfr[4];
#pragma unroll
      for (int nj = 0; nj < 4; ++nj)
        bfr[nj] = *(const short8*)&Bsh[(nj * 16 + r) * LROW + ks * 32 + kg * 8];
#pragma unroll
      for (int mi = 0; mi < 2; ++mi)
#pragma unroll
        for (int nj = 0; nj < 4; ++nj)
          acc[mi][nj] = __builtin_amdgcn_mfma_f32_16x16x32_bf16(afr[mi], bfr[nj], acc[mi][nj], 0, 0, 0);
    }
  }
  const size_t base = ((size_t)kc << 20) + (size_t)b * (256 * 512);
#pragma unroll
  for (int mi = 0; mi < 2; ++mi)
#pragma unroll
    for (int nj = 0; nj < 4; ++nj)
#pragma unroll
      for (int reg = 0; reg < 4; ++reg) {
        const int f = fbase + mi * 16 + kg * 4 + reg;
        const int a = a0 + nj * 16 + r;
        partial[base + (size_t)f * 512 + a] = acc[mi][nj][reg];
      }
}

// ---------------------------------------------------------------------------
// k_ctxred: ctx[idx] = (1/rsum[row_a]) * sum_kc partial[kc][idx]
// ---------------------------------------------------------------------------
__global__ __launch_bounds__(256) void k_ctxred(
    const float* __restrict__ partial, const float* __restrict__ rsum,
    float* __restrict__ ctx) {
  const int idx = blockIdx.x * 256 + threadIdx.x;
  const int a = idx & 511, b = idx >> 17;
  float s = 0.f;
#pragma unroll
  for (int kc = 0; kc < 8; ++kc) s += partial[((size_t)kc << 20) + idx];
  ctx[idx] = s / rsum[b * 512 + a];
}

// ---------------------------------------------------------------------------
// k_attn_out: attn[row,p] = e_bf16[row,p] / rsum[row]  (f32 out)
// ---------------------------------------------------------------------------
__global__ __launch_bounds__(256) void k_attn_out(
    const unsigned short* __restrict__ attbf, const float* __restrict__ rsum,
    float* __restrict__ attn) {
  const int row = blockIdx.x;
  const float inv = 1.0f / rsum[row];
  const unsigned short* src = attbf + (size_t)row * HW;
  float* dst = attn + (size_t)row * HW;
  const int tid = threadIdx.x;
#pragma unroll
  for (int i = 0; i < 2; ++i) {
    short8 v = *(const short8*)(src + tid * 8 + i * 2048);
    float4 o0, o1;
    o0.x = bf2f((unsigned short)v[0]) * inv;
    o0.y = bf2f((unsigned short)v[1]) * inv;
    o0.z = bf2f((unsigned short)v[2]) * inv;
    o0.w = bf2f((unsigned short)v[3]) * inv;
    o1.x = bf2f((unsigned short)v[4]) * inv;
    o1.y = bf2f((unsigned short)v[5]) * inv;
    o1.z = bf2f((unsigned short)v[6]) * inv;
    o1.w = bf2f((unsigned short)v[7]) * inv;
    *(float4*)(dst + tid * 8 + i * 2048) = o0;
    *(float4*)(dst + tid * 8 + i * 2048 + 4) = o1;
  }
}

// ---------------------------------------------------------------------------
extern "C" void kernel_launch(void* const* d_in, const int* in_sizes, int n_in,
                              void* d_out, int out_size, void* d_ws, size_t ws_size,
                              hipStream_t stream) {
  const float* x     = (const float*)d_in[0];
  const float* Wf    = (const float*)d_in[1];
  const float* bfeat = (const float*)d_in[2];
  const float* Wa    = (const float*)d_in[3];
  const float* ba    = (const float*)d_in[4];
  float* ctx  = (float*)d_out;
  float* attn = ctx + CTX_ELEMS;

  unsigned short* featbf = (unsigned short*)d_ws;                 // 16.8 MB
  unsigned short* attbf  = featbf + (size_t)NB * 256 * HW;        // 33.6 MB
  float* rsum_part = (float*)(attbf + (size_t)4096 * HW);         // 512 KB
  float* rsum = rsum_part + 32 * 4096;                            // 16 KB
  float* partial = attn;   // reuse attn slot as split-K scratch (overwritten by k_attn_out last)

  k_feat<<<dim3(32, 2, NB), 256, 0, stream>>>(x, Wf, bfeat, featbf);
  k_att<<<dim3(32, 64), 256, 0, stream>>>(x, Wa, ba, attbf, rsum_part);
  k_rsum<<<16, 256, 0, stream>>>(rsum_part, rsum);
  k_ctx<<<dim3(8, 2, 64), 256, 0, stream>>>(featbf, attbf, partial);
  k_ctxred<<<4096, 256, 0, stream>>>(partial, rsum, ctx);
  k_attn_out<<<4096, 256, 0, stream>>>(attbf, rsum, attn);
}